// Round 1
// 1532.068 us; speedup vs baseline: 1.1218x; 1.1218x over previous
//
#include <hip/hip_runtime.h>
#include <stdint.h>

#define N_NODES   50000
#define N_GENES   512
#define N_EDGES   800000
#define N_ITERS   5

#define C_CHUNKS  250
#define CHUNK_E   3200          // 250 * 3200 = 800000; 3200/64 = 50 subchunks exactly

// ---- packed-sparse x representation ----
// Per row: 64 aux dwords (one per lane): bits 0..7  = nonzero mask for the lane's
//          8 genes {4l..4l+3, 256+4l..256+4l+3}; bits 8..15 = rank base of the
//          lane's first-half quad (count of nonzeros in genes < 4l, <=252 fits u8);
//          bits 16..23 = rank base within second half (genes 256..256+4l-1).
// Values: nonzeros in ascending gene order, fixed stride VSTRIDE floats per row.
// Bound: nnz(row) <= orig_nnz(row) + cap(row) <= orig_nnz + 127. orig_nnz ~
// Binom(512,0.1) (mean 51.2, sd 6.8) -> P(orig_nnz > 193) ~ 20 sigma. VSTRIDE=320 safe.
#define VSTRIDE    320
#define VROW_BYTES (VSTRIDE * 4)

// ws layout sizes (bytes)
#define VALS_A_BYTES  (50000ull * VROW_BYTES + 256ull)  // +pad for speculative tail loads
#define AUX_A_BYTES   (50000ull * 256ull)
#define IMP_BYTES     3200000ull
#define CNT_BYTES     200000ull
#define PTR_BYTES     200004ull
#define CCOL_BYTES    3200000ull
#define CW_BYTES      3200000ull
#define WS_NEEDED (VALS_A_BYTES + AUX_A_BYTES + IMP_BYTES + CNT_BYTES + PTR_BYTES + CCOL_BYTES + CW_BYTES)
// hist (250*50000*4 = 50 MB) aliases the vals_a region: dead before vals_a first written.
// Buffer B (vals_b + aux_b = 76.8 MB) aliases d_out (102.4 MB): dense out written only
// by the last iteration, which reads buffer A.

// ---------- JAX threefry2x32 (20 rounds), exact replica ----------
__host__ __device__ __forceinline__ uint32_t rotl32(uint32_t x, int r) {
  return (x << r) | (x >> (32 - r));
}

__host__ __device__ __forceinline__ void threefry2x32(uint32_t k0, uint32_t k1,
                                                      uint32_t x0, uint32_t x1,
                                                      uint32_t& o0, uint32_t& o1) {
  uint32_t k2 = k0 ^ k1 ^ 0x1BD11BDAu;
  x0 += k0; x1 += k1;
  x0 += x1; x1 = rotl32(x1, 13) ^ x0;
  x0 += x1; x1 = rotl32(x1, 15) ^ x0;
  x0 += x1; x1 = rotl32(x1, 26) ^ x0;
  x0 += x1; x1 = rotl32(x1, 6)  ^ x0;
  x0 += k1; x1 += k2 + 1u;
  x0 += x1; x1 = rotl32(x1, 17) ^ x0;
  x0 += x1; x1 = rotl32(x1, 29) ^ x0;
  x0 += x1; x1 = rotl32(x1, 16) ^ x0;
  x0 += x1; x1 = rotl32(x1, 24) ^ x0;
  x0 += k2; x1 += k0 + 2u;
  x0 += x1; x1 = rotl32(x1, 13) ^ x0;
  x0 += x1; x1 = rotl32(x1, 15) ^ x0;
  x0 += x1; x1 = rotl32(x1, 26) ^ x0;
  x0 += x1; x1 = rotl32(x1, 6)  ^ x0;
  x0 += k0; x1 += k1 + 3u;
  x0 += x1; x1 = rotl32(x1, 17) ^ x0;
  x0 += x1; x1 = rotl32(x1, 29) ^ x0;
  x0 += x1; x1 = rotl32(x1, 16) ^ x0;
  x0 += x1; x1 = rotl32(x1, 24) ^ x0;
  x0 += k1; x1 += k2 + 4u;
  x0 += x1; x1 = rotl32(x1, 13) ^ x0;
  x0 += x1; x1 = rotl32(x1, 15) ^ x0;
  x0 += x1; x1 = rotl32(x1, 26) ^ x0;
  x0 += x1; x1 = rotl32(x1, 6)  ^ x0;
  x0 += k2; x1 += k0 + 5u;
  o0 = x0; o1 = x1;
}

__device__ __forceinline__ uint32_t jax_bits_part32(uint32_t k0, uint32_t k1, uint32_t j) {
  uint32_t o0, o1;
  threefry2x32(k0, k1, 0u, j, o0, o1);
  return o0 ^ o1;
}

// ---------- order-preserving CSR build (unchanged) ----------
__global__ void chunk_hist(const int* __restrict__ rows, int* __restrict__ hist) {
  int c = blockIdx.x;
  int base = c * CHUNK_E;
  int* h = hist + (size_t)c * N_NODES;
  for (int i = threadIdx.x; i < CHUNK_E; i += blockDim.x)
    atomicAdd(&h[rows[base + i]], 1);
}

__global__ void row_scan(int* __restrict__ hist, int* __restrict__ cnt) {
  int r = blockIdx.x * blockDim.x + threadIdx.x;
  if (r >= N_NODES) return;
  int run = 0;
  for (int c = 0; c < C_CHUNKS; ++c) {
    size_t idx = (size_t)c * N_NODES + r;
    int t = hist[idx];
    hist[idx] = run;
    run += t;
  }
  cnt[r] = run;
}

__global__ void scan_counts(int* __restrict__ cnt, int* __restrict__ ptr) {
  const int T = 256;
  const int CH = (N_NODES + T - 1) / T;
  __shared__ int sums[T];
  int t = threadIdx.x;
  int lo = t * CH;
  int hi = min(lo + CH, N_NODES);
  int s = 0;
  for (int i = lo; i < hi; ++i) s += cnt[i];
  sums[t] = s;
  __syncthreads();
  for (int off = 1; off < T; off <<= 1) {
    int u = (t >= off) ? sums[t - off] : 0;
    __syncthreads();
    sums[t] += u;
    __syncthreads();
  }
  int run = sums[t] - s;
  for (int i = lo; i < hi; ++i) { int c = cnt[i]; ptr[i] = run; run += c; }
  if (t == T - 1) ptr[N_NODES] = run;
}

__global__ __launch_bounds__(64) void scatter_par(
    const int* __restrict__ rows, const int* __restrict__ cols,
    const float* __restrict__ w, const int* __restrict__ ptr,
    int* __restrict__ hist, int* __restrict__ ccol, float* __restrict__ cw) {
  int c = blockIdx.x;
  int lane = threadIdx.x;
  int* h = hist + (size_t)c * N_NODES;
  int base = c * CHUNK_E;
  for (int sub = 0; sub < CHUNK_E / 64; ++sub) {
    int e = base + sub * 64 + lane;
    int r = rows[e];
    int rank = 0, count = 0, lastlane = 0;
    #pragma unroll 8
    for (int i = 0; i < 64; ++i) {
      int ri = __shfl(r, i, 64);
      if (ri == r) {
        count++;
        if (i < lane) rank++;
        lastlane = i;
      }
    }
    int old = 0;
    if (lane == lastlane) old = atomicAdd(&h[r], count);
    old = __shfl(old, lastlane, 64);
    int pos = ptr[r] + old + rank;
    ccol[pos] = cols[e];
    cw[pos]   = w[e];
  }
}

// ---------- packed row read: aux dword + 8 speculative value loads ----------
// Speculative loads may read up to 3 floats past this row's nnz (still inside the
// row's 320-float stride or the 256-B buffer pad); garbage lanes are cndmask'd to 0
// before any arithmetic, so NaN/uninit bytes never propagate.
__device__ __forceinline__ void unpack_row(const uint32_t* __restrict__ aux,
                                           const float* __restrict__ vals,
                                           int row, int lane, float* v) {
  uint32_t ax = aux[(size_t)row * 64 + lane];
  uint32_t mb = ax & 255u;
  int rF = (int)((ax >> 8) & 255u);
  int rS = (int)((ax >> 16) & 255u);
  int tF = rF + __popc(mb & 15u);
  tF = __shfl(tF, 63, 64);          // total first-half nnz from lane 63
  const float* vr = vals + (size_t)row * VSTRIDE;
  int o1 = rF + (int)(mb & 1u);
  int o2 = rF + __popc(mb & 3u);
  int o3 = rF + __popc(mb & 7u);
  float a0 = vr[rF], a1 = vr[o1], a2 = vr[o2], a3 = vr[o3];
  int b0 = tF + rS;
  uint32_t mh = mb >> 4;
  int p1 = b0 + (int)(mh & 1u);
  int p2 = b0 + __popc(mh & 3u);
  int p3 = b0 + __popc(mh & 7u);
  float a4 = vr[b0], a5 = vr[p1], a6 = vr[p2], a7 = vr[p3];
  v[0] = (mb & 1u)   ? a0 : 0.f;
  v[1] = (mb & 2u)   ? a1 : 0.f;
  v[2] = (mb & 4u)   ? a2 : 0.f;
  v[3] = (mb & 8u)   ? a3 : 0.f;
  v[4] = (mh & 1u)   ? a4 : 0.f;
  v[5] = (mh & 2u)   ? a5 : 0.f;
  v[6] = (mh & 4u)   ? a6 : 0.f;
  v[7] = (mh & 8u)   ? a7 : 0.f;
}

// ---------- packed row write: mask + two lane prefix-scans, rank-packed values ----------
__device__ __forceinline__ void pack_row(uint32_t* __restrict__ aux,
                                         float* __restrict__ vals,
                                         int row, int lane, const float* rv) {
  uint32_t vm = 0;
  #pragma unroll
  for (int j = 0; j < 8; ++j) vm |= (rv[j] != 0.f) ? (1u << j) : 0u;
  int pF = __popc(vm & 15u);
  int pS = __popc(vm >> 4);
  int iF = pF, iS = pS;
  #pragma unroll
  for (int off = 1; off < 64; off <<= 1) {
    int uF = __shfl_up(iF, off, 64);
    int uS = __shfl_up(iS, off, 64);
    if (lane >= off) { iF += uF; iS += uS; }
  }
  int rF = iF - pF, rS = iS - pS;         // exclusive prefixes, <= 252 each
  int tF = __shfl(iF, 63, 64);            // total first-half nnz
  aux[(size_t)row * 64 + lane] = vm | ((uint32_t)rF << 8) | ((uint32_t)rS << 16);
  float* vr = vals + (size_t)row * VSTRIDE;
  int o = rF;
  #pragma unroll
  for (int j = 0; j < 4; ++j) if (vm & (1u << j)) vr[o++] = rv[j];
  o = tF + rS;
  #pragma unroll
  for (int j = 4; j < 8; ++j) if (vm & (1u << j)) vr[o++] = rv[j];
}

// initial pack of dense x_in -> buffer A
__global__ __launch_bounds__(256) void init_pack(const float* __restrict__ x,
                                                 uint32_t* __restrict__ aux,
                                                 float* __restrict__ vals) {
  int wv = threadIdx.x >> 6, lane = threadIdx.x & 63;
  int r = blockIdx.x * 4 + wv;
  const float4* p4 = (const float4*)(x + (size_t)r * N_GENES);
  float4 pa = p4[lane], pb = p4[64 + lane];
  float rv[8] = {pa.x, pa.y, pa.z, pa.w, pb.x, pb.y, pb.z, pb.w};
  pack_row(aux, vals, r, lane, rv);
}

// transposed LDS index for bucket b
__device__ __forceinline__ int tr(uint32_t b) {
  return (int)(((b & 3u) << 6) | (b >> 2));
}

// ---------- fused propagate + select over packed-sparse x ----------
// Zero entries contribute acc += w*0.0 == acc exactly (only sign-of-zero can differ,
// which neither the !=0 tests nor absmax observe), so skipping them via the packed
// format is bit-equivalent to the dense FMA chain. Edge order per gene preserved;
// mul/add rounded separately (contract off) to match XLA segment_sum.
template <bool LAST>
__global__ __launch_bounds__(256) void prop_select(
    const uint32_t* __restrict__ aux_p, const float* __restrict__ vals_p,
    const int* __restrict__ ptr, const int* __restrict__ ccol,
    const float* __restrict__ cw, unsigned char* __restrict__ imp,
    const int* __restrict__ cap_arr, uint32_t k0, uint32_t k1,
    uint32_t* __restrict__ aux_n, float* __restrict__ vals_n,
    float* __restrict__ xdense) {
  #pragma clang fp contract(off)
  __shared__ int hist_s[4][256];
  int wv = threadIdx.x >> 6;
  int lane = threadIdx.x & 63;
  int r = blockIdx.x * 4 + wv;
  int beg = ptr[r], end = ptr[r + 1];
  int* h = hist_s[wv];

  // hoist row-r merge inputs: overlap their latency with the gather
  unsigned char ibyte = imp[(size_t)r * 64 + lane];
  int cap = cap_arr[r];
  float pv[8];
  unpack_row(aux_p, vals_p, r, lane, pv);

  // ---- gather-accumulate xp for this row (exact ascending edge order) ----
  float acc[8] = {0.f, 0.f, 0.f, 0.f, 0.f, 0.f, 0.f, 0.f};
  for (int base = beg; base < end; base += 64) {
    int n = min(64, end - base);
    int c = 0; float wt = 0.f;
    if (lane < n) { c = ccol[base + lane]; wt = cw[base + lane]; }
    int i = 0;
    for (; i + 1 < n; i += 2) {
      int   c0 = __shfl(c, i, 64),      c1 = __shfl(c, i + 1, 64);
      float w0 = __shfl(wt, i, 64),     w1 = __shfl(wt, i + 1, 64);
      float v0[8], v1[8];
      unpack_row(aux_p, vals_p, c0, lane, v0);
      unpack_row(aux_p, vals_p, c1, lane, v1);
      #pragma unroll
      for (int j = 0; j < 8; ++j) acc[j] = acc[j] + w0 * v0[j];
      #pragma unroll
      for (int j = 0; j < 8; ++j) acc[j] = acc[j] + w1 * v1[j];
    }
    if (i < n) {
      int   c0 = __shfl(c, i, 64);
      float w0 = __shfl(wt, i, 64);
      float v0[8];
      unpack_row(aux_p, vals_p, c0, lane, v0);
      #pragma unroll
      for (int j = 0; j < 8; ++j) acc[j] = acc[j] + w0 * v0[j];
    }
  }

  // ---- merge: existing (orig nonzero) entries win ----
  float val[8];
  bool ex[8];
  #pragma unroll
  for (int j = 0; j < 8; ++j) {
    ex[j] = (pv[j] != 0.f) && !((ibyte >> j) & 1);
    val[j] = ex[j] ? pv[j] : acc[j];
  }

  // ---- valid mask & count ----
  bool valid[8];
  int cnt_local = 0;
  #pragma unroll
  for (int j = 0; j < 8; ++j) {
    bool im = ((ibyte >> j) & 1) || ((val[j] != 0.f) && !ex[j]);
    valid[j] = im;
    cnt_local += im ? 1 : 0;
  }
  int nimp = cnt_local;
  #pragma unroll
  for (int off = 32; off > 0; off >>= 1) nimp += __shfl_xor(nimp, off, 64);

  bool keep_all = (nimp <= cap);
  bool keep_none = (!keep_all) && (cap <= 0);
  uint32_t key[8];
  uint32_t T = 0;
  bool use_T = false;

  if (!keep_all && !keep_none) {   // wave-uniform branch
    uint32_t goff = (uint32_t)r * (uint32_t)N_GENES;
    #pragma unroll
    for (int j = 0; j < 8; ++j) {
      int g = (j < 4) ? (4 * lane + j) : (256 + 4 * lane + (j - 4));
      uint32_t b = jax_bits_part32(k0, k1, goff + (uint32_t)g);
      key[j] = ((b >> 9) << 9) | (uint32_t)g;
    }
    h[lane] = 0; h[lane + 64] = 0; h[lane + 128] = 0; h[lane + 192] = 0;
    #pragma unroll
    for (int j = 0; j < 8; ++j)
      if (valid[j]) atomicAdd(&h[tr(key[j] >> 24)], 1);
    __threadfence_block();
    int c0 = h[lane], c1 = h[64 + lane], c2 = h[128 + lane], c3 = h[192 + lane];
    int lsum = c0 + c1 + c2 + c3;
    int incl = lsum;
    #pragma unroll
    for (int off = 1; off < 64; off <<= 1) {
      int v = __shfl_up(incl, off, 64);
      if (lane >= off) incl += v;
    }
    int excl = incl - lsum;
    int foundB = -1, foundRem = 0, cum = excl;
    if (cap > cum && cap <= cum + c0) { foundB = 4 * lane;     foundRem = cap - cum; } cum += c0;
    if (foundB < 0 && cap > cum && cap <= cum + c1) { foundB = 4 * lane + 1; foundRem = cap - cum; } cum += c1;
    if (foundB < 0 && cap > cum && cap <= cum + c2) { foundB = 4 * lane + 2; foundRem = cap - cum; } cum += c2;
    if (foundB < 0 && cap > cum && cap <= cum + c3) { foundB = 4 * lane + 3; foundRem = cap - cum; }
    unsigned long long mb = __ballot(foundB >= 0);
    int src = __ffsll(mb) - 1;
    int B   = __shfl(foundB, src, 64);
    int rem = __shfl(foundRem, src, 64);
    unsigned cm = 0;
    #pragma unroll
    for (int j = 0; j < 8; ++j)
      if (valid[j] && (int)(key[j] >> 24) == B) cm |= (1u << j);
    for (;;) {
      uint32_t m = 0xFFFFFFFFu;
      #pragma unroll
      for (int j = 0; j < 8; ++j)
        if (cm & (1u << j)) m = min(m, key[j]);
      #pragma unroll
      for (int off = 32; off > 0; off >>= 1)
        m = min(m, (uint32_t)__shfl_xor((int)m, off, 64));
      if (rem == 1) { T = m; break; }
      #pragma unroll
      for (int j = 0; j < 8; ++j)
        if ((cm & (1u << j)) && key[j] == m) cm &= ~(1u << j);
      rem--;
    }
    use_T = true;
  }

  // ---- apply & write ----
  float rv[8]; unsigned char ob8 = 0;
  #pragma unroll
  for (int j = 0; j < 8; ++j) {
    bool keep = valid[j] && (keep_all || (use_T && key[j] <= T));
    ob8 |= (unsigned char)(keep ? (1u << j) : 0u);
    rv[j] = (valid[j] && !keep) ? 0.f : val[j];
  }
  if (LAST) {
    // final iteration: dense output only (imp no longer needed)
    float4* x4 = (float4*)(xdense + (size_t)r * N_GENES);
    x4[lane]      = make_float4(rv[0], rv[1], rv[2], rv[3]);
    x4[64 + lane] = make_float4(rv[4], rv[5], rv[6], rv[7]);
  } else {
    pack_row(aux_n, vals_n, r, lane, rv);
    imp[(size_t)r * 64 + lane] = ob8;
  }
}

// diagnostic: only fires if workspace is smaller than we need
__global__ void ws_probe(float* out, unsigned long long ws_bytes, unsigned long long needed) {
  if (ws_bytes < needed) out[0] = (float)ws_bytes;
}

extern "C" void kernel_launch(void* const* d_in, const int* in_sizes, int n_in,
                              void* d_out, int out_size, void* d_ws, size_t ws_size,
                              hipStream_t stream) {
  const float* x_in = (const float*)d_in[0];
  const float* ew   = (const float*)d_in[1];
  const int*   ei   = (const int*)d_in[2];
  const int*   cap  = (const int*)d_in[3];
  const int* rows = ei;
  const int* cols = ei + N_EDGES;
  float* out = (float*)d_out;

  char* ws = (char*)d_ws;
  float* vals_a = (float*)ws;               ws += VALS_A_BYTES;
  uint32_t* aux_a = (uint32_t*)ws;          ws += AUX_A_BYTES;
  unsigned char* imp = (unsigned char*)ws;  ws += IMP_BYTES;
  int* cnt = (int*)ws;                      ws += CNT_BYTES;
  int* ptr = (int*)ws;                      ws += PTR_BYTES;
  int* ccol = (int*)ws;                     ws += CCOL_BYTES;
  float* cw = (float*)ws;                   ws += CW_BYTES;
  int* hist = (int*)d_ws;   // aliases vals_a: 50 MB, dead before vals_a first written

  // buffer B aliases d_out (dense out written only by the last iteration, which reads A)
  float* vals_b = (float*)d_out;
  uint32_t* aux_b = (uint32_t*)((char*)d_out + VALS_A_BYTES);

  hipMemsetAsync(hist, 0, (size_t)C_CHUNKS * N_NODES * sizeof(int), stream);
  hipMemsetAsync(imp, 0, IMP_BYTES, stream);

  chunk_hist<<<C_CHUNKS, 256, 0, stream>>>(rows, hist);
  row_scan<<<(N_NODES + 255) / 256, 256, 0, stream>>>(hist, cnt);
  scan_counts<<<1, 256, 0, stream>>>(cnt, ptr);
  scatter_par<<<C_CHUNKS, 64, 0, stream>>>(rows, cols, ew, ptr, hist, ccol, cw);
  init_pack<<<N_NODES / 4, 256, 0, stream>>>(x_in, aux_a, vals_a);

  uint32_t key_it[N_ITERS][2];
  for (int it = 0; it < N_ITERS; ++it) {
    uint32_t o0, o1;
    threefry2x32(0u, 42u, 0u, (uint32_t)it, o0, o1);
    key_it[it][0] = o0; key_it[it][1] = o1;
  }

  for (int it = 0; it < N_ITERS - 1; ++it) {
    bool a2b = (it & 1) == 0;   // it0: A->B, it1: B->A, it2: A->B, it3: B->A
    prop_select<false><<<N_NODES / 4, 256, 0, stream>>>(
        a2b ? aux_a : aux_b, a2b ? vals_a : vals_b,
        ptr, ccol, cw, imp, cap, key_it[it][0], key_it[it][1],
        a2b ? aux_b : aux_a, a2b ? vals_b : vals_a, nullptr);
  }
  // it4 reads A, writes dense to out (clobbering B, which is dead)
  prop_select<true><<<N_NODES / 4, 256, 0, stream>>>(
      aux_a, vals_a, ptr, ccol, cw, imp, cap,
      key_it[N_ITERS - 1][0], key_it[N_ITERS - 1][1],
      nullptr, nullptr, out);

  ws_probe<<<1, 1, 0, stream>>>(out, (unsigned long long)ws_size,
                                (unsigned long long)WS_NEEDED);
}

// Round 2
// 1446.417 us; speedup vs baseline: 1.1882x; 1.0592x over previous
//
#include <hip/hip_runtime.h>
#include <stdint.h>

#define N_NODES   50000
#define N_GENES   512
#define N_EDGES   800000
#define N_ITERS   5

#define C_CHUNKS  250
#define CHUNK_E   3200          // 250 * 3200 = 800000; 3200/64 = 50 subchunks exactly

// ---- packed-sparse x representation (one 1536-B record per row) ----
// rec[0..63]   : aux dwords, one per lane. bits[7:0] = nonzero mask for the lane's
//                8 genes {4l..4l+3, 256+4l..256+4l+3}; bits[15:8] = rF = rank of
//                gene 4l among first-half nonzeros (<=252, u8); bits[24:16] = b0 =
//                absolute packed position of the lane's first second-half value
//                (= totF + rS, <= 320, 9 bits).
// rec[64..383] : packed nonzero values, ascending gene order (<=320 floats).
// Bound: nnz(row) <= orig_nnz + cap <= ~193+127 (orig_nnz>193 is ~20 sigma). 320 safe.
#define REC_DW     384
#define REC_BYTES  1536
#define VALS_OFF   64          // dword offset of values inside record

// ws layout sizes (bytes)
#define RECS_BYTES (50000ull * REC_BYTES + 256ull)  // +pad for speculative tail reads
#define IMP_BYTES  3200000ull
#define CNT_BYTES  200000ull
#define PTR_BYTES  200004ull
#define CCOL_BYTES 3200000ull
#define CW_BYTES   3200000ull
#define WS_NEEDED (RECS_BYTES + IMP_BYTES + CNT_BYTES + PTR_BYTES + CCOL_BYTES + CW_BYTES)
// hist (250*50000*4 = 50 MB) aliases recs_a: dead before recs_a first written.
// Buffer B (recs_b, 76.8 MB) aliases d_out (102.4 MB): dense out written only by the
// last iteration, which reads buffer A.

// ---------- JAX threefry2x32 (20 rounds), exact replica ----------
__host__ __device__ __forceinline__ uint32_t rotl32(uint32_t x, int r) {
  return (x << r) | (x >> (32 - r));
}

__host__ __device__ __forceinline__ void threefry2x32(uint32_t k0, uint32_t k1,
                                                      uint32_t x0, uint32_t x1,
                                                      uint32_t& o0, uint32_t& o1) {
  uint32_t k2 = k0 ^ k1 ^ 0x1BD11BDAu;
  x0 += k0; x1 += k1;
  x0 += x1; x1 = rotl32(x1, 13) ^ x0;
  x0 += x1; x1 = rotl32(x1, 15) ^ x0;
  x0 += x1; x1 = rotl32(x1, 26) ^ x0;
  x0 += x1; x1 = rotl32(x1, 6)  ^ x0;
  x0 += k1; x1 += k2 + 1u;
  x0 += x1; x1 = rotl32(x1, 17) ^ x0;
  x0 += x1; x1 = rotl32(x1, 29) ^ x0;
  x0 += x1; x1 = rotl32(x1, 16) ^ x0;
  x0 += x1; x1 = rotl32(x1, 24) ^ x0;
  x0 += k2; x1 += k0 + 2u;
  x0 += x1; x1 = rotl32(x1, 13) ^ x0;
  x0 += x1; x1 = rotl32(x1, 15) ^ x0;
  x0 += x1; x1 = rotl32(x1, 26) ^ x0;
  x0 += x1; x1 = rotl32(x1, 6)  ^ x0;
  x0 += k0; x1 += k1 + 3u;
  x0 += x1; x1 = rotl32(x1, 17) ^ x0;
  x0 += x1; x1 = rotl32(x1, 29) ^ x0;
  x0 += x1; x1 = rotl32(x1, 16) ^ x0;
  x0 += x1; x1 = rotl32(x1, 24) ^ x0;
  x0 += k1; x1 += k2 + 4u;
  x0 += x1; x1 = rotl32(x1, 13) ^ x0;
  x0 += x1; x1 = rotl32(x1, 15) ^ x0;
  x0 += x1; x1 = rotl32(x1, 26) ^ x0;
  x0 += x1; x1 = rotl32(x1, 6)  ^ x0;
  x0 += k2; x1 += k0 + 5u;
  o0 = x0; o1 = x1;
}

__device__ __forceinline__ uint32_t jax_bits_part32(uint32_t k0, uint32_t k1, uint32_t j) {
  uint32_t o0, o1;
  threefry2x32(k0, k1, 0u, j, o0, o1);
  return o0 ^ o1;
}

// ---------- order-preserving CSR build (unchanged) ----------
__global__ void chunk_hist(const int* __restrict__ rows, int* __restrict__ hist) {
  int c = blockIdx.x;
  int base = c * CHUNK_E;
  int* h = hist + (size_t)c * N_NODES;
  for (int i = threadIdx.x; i < CHUNK_E; i += blockDim.x)
    atomicAdd(&h[rows[base + i]], 1);
}

__global__ void row_scan(int* __restrict__ hist, int* __restrict__ cnt) {
  int r = blockIdx.x * blockDim.x + threadIdx.x;
  if (r >= N_NODES) return;
  int run = 0;
  for (int c = 0; c < C_CHUNKS; ++c) {
    size_t idx = (size_t)c * N_NODES + r;
    int t = hist[idx];
    hist[idx] = run;
    run += t;
  }
  cnt[r] = run;
}

__global__ void scan_counts(int* __restrict__ cnt, int* __restrict__ ptr) {
  const int T = 256;
  const int CH = (N_NODES + T - 1) / T;
  __shared__ int sums[T];
  int t = threadIdx.x;
  int lo = t * CH;
  int hi = min(lo + CH, N_NODES);
  int s = 0;
  for (int i = lo; i < hi; ++i) s += cnt[i];
  sums[t] = s;
  __syncthreads();
  for (int off = 1; off < T; off <<= 1) {
    int u = (t >= off) ? sums[t - off] : 0;
    __syncthreads();
    sums[t] += u;
    __syncthreads();
  }
  int run = sums[t] - s;
  for (int i = lo; i < hi; ++i) { int c = cnt[i]; ptr[i] = run; run += c; }
  if (t == T - 1) ptr[N_NODES] = run;
}

__global__ __launch_bounds__(64) void scatter_par(
    const int* __restrict__ rows, const int* __restrict__ cols,
    const float* __restrict__ w, const int* __restrict__ ptr,
    int* __restrict__ hist, int* __restrict__ ccol, float* __restrict__ cw) {
  int c = blockIdx.x;
  int lane = threadIdx.x;
  int* h = hist + (size_t)c * N_NODES;
  int base = c * CHUNK_E;
  for (int sub = 0; sub < CHUNK_E / 64; ++sub) {
    int e = base + sub * 64 + lane;
    int r = rows[e];
    int rank = 0, count = 0, lastlane = 0;
    #pragma unroll 8
    for (int i = 0; i < 64; ++i) {
      int ri = __shfl(r, i, 64);
      if (ri == r) {
        count++;
        if (i < lane) rank++;
        lastlane = i;
      }
    }
    int old = 0;
    if (lane == lastlane) old = atomicAdd(&h[r], count);
    old = __shfl(old, lastlane, 64);
    int pos = ptr[r] + old + rank;
    ccol[pos] = cols[e];
    cw[pos]   = w[e];
  }
}

// ---------- pack: mask + two lane prefix-scans, rank-packed values ----------
__device__ __forceinline__ void pack_row(uint32_t* __restrict__ rec,
                                         int lane, const float* rv) {
  uint32_t vm = 0;
  #pragma unroll
  for (int j = 0; j < 8; ++j) vm |= (rv[j] != 0.f) ? (1u << j) : 0u;
  int pF = __popc(vm & 15u);
  int pS = __popc(vm >> 4);
  int iF = pF, iS = pS;
  #pragma unroll
  for (int off = 1; off < 64; off <<= 1) {
    int uF = __shfl_up(iF, off, 64);
    int uS = __shfl_up(iS, off, 64);
    if (lane >= off) { iF += uF; iS += uS; }
  }
  int rF = iF - pF, rS = iS - pS;          // exclusive prefixes
  int tF = __shfl(iF, 63, 64);             // total first-half nnz
  int b0 = tF + rS;                        // absolute base of lane's 2nd-half vals
  rec[lane] = vm | ((uint32_t)rF << 8) | ((uint32_t)b0 << 16);
  float* vr = (float*)(rec + VALS_OFF);
  int o = rF;
  #pragma unroll
  for (int j = 0; j < 4; ++j) if (vm & (1u << j)) vr[o++] = rv[j];
  o = b0;
  #pragma unroll
  for (int j = 4; j < 8; ++j) if (vm & (1u << j)) vr[o++] = rv[j];
}

// scalar unpack (used once per wave for row r's own previous values)
__device__ __forceinline__ void unpack_row_scalar(const uint32_t* __restrict__ rec,
                                                  int lane, float* v) {
  uint32_t ax = rec[lane];
  uint32_t mb = ax & 255u, mh = mb >> 4;
  int rF = (int)((ax >> 8) & 255u);
  int b0 = (int)((ax >> 16) & 511u);
  const float* vr = (const float*)(rec + VALS_OFF);
  int p1 = rF + (int)(mb & 1u);
  int p2 = rF + __popc(mb & 3u);
  int p3 = rF + __popc(mb & 7u);
  int q1 = b0 + (int)(mh & 1u);
  int q2 = b0 + __popc(mh & 3u);
  int q3 = b0 + __popc(mh & 7u);
  float a0 = vr[rF], a1 = vr[p1], a2 = vr[p2], a3 = vr[p3];
  float a4 = vr[b0], a5 = vr[q1], a6 = vr[q2], a7 = vr[q3];
  v[0] = (mb & 1u) ? a0 : 0.f;
  v[1] = (mb & 2u) ? a1 : 0.f;
  v[2] = (mb & 4u) ? a2 : 0.f;
  v[3] = (mb & 8u) ? a3 : 0.f;
  v[4] = (mh & 1u) ? a4 : 0.f;
  v[5] = (mh & 2u) ? a5 : 0.f;
  v[6] = (mh & 4u) ? a6 : 0.f;
  v[7] = (mh & 8u) ? a7 : 0.f;
}

// initial pack of dense x_in -> buffer A
__global__ __launch_bounds__(256) void init_pack(const float* __restrict__ x,
                                                 uint32_t* __restrict__ recs) {
  int wv = threadIdx.x >> 6, lane = threadIdx.x & 63;
  int r = blockIdx.x * 4 + wv;
  const float4* p4 = (const float4*)(x + (size_t)r * N_GENES);
  float4 pa = p4[lane], pb = p4[64 + lane];
  float rv[8] = {pa.x, pa.y, pa.z, pa.w, pb.x, pb.y, pb.z, pb.w};
  pack_row(recs + (size_t)r * REC_DW, lane, rv);
}

// transposed LDS index for bucket b
__device__ __forceinline__ int tr(uint32_t b) {
  return (int)(((b & 3u) << 6) | (b >> 2));
}

__device__ __forceinline__ float readlane_f(float v, int i) {
  return __int_as_float(__builtin_amdgcn_readlane(__float_as_int(v), i));
}

// ---------- fused propagate + select over packed-sparse x ----------
// Gather per edge: aux dword + 3 positional value dwords load IN PARALLEL (no
// aux->address dependency); values staged in per-wave ping-pong LDS; rank-indexed
// gather via conflict-free ds_read (positions nondecreasing across lanes).
// Zero entries contribute acc += w*0.0 == acc exactly; per-gene FMA order is the
// ascending edge order, mul/add rounded separately (contract off) == XLA segment_sum.
template <bool LAST>
__global__ __launch_bounds__(256) void prop_select(
    const uint32_t* __restrict__ recs_p,
    const int* __restrict__ ptr, const int* __restrict__ ccol,
    const float* __restrict__ cw, unsigned char* __restrict__ imp,
    const int* __restrict__ cap_arr, uint32_t k0, uint32_t k1,
    uint32_t* __restrict__ recs_n, float* __restrict__ xdense) {
  #pragma clang fp contract(off)
  __shared__ int hist_s[4][256];
  __shared__ float vbuf[4][2][256];   // per-wave ping-pong value stage (192 used)
  int wv = threadIdx.x >> 6;
  int lane = threadIdx.x & 63;
  int r = blockIdx.x * 4 + wv;
  int beg = ptr[r], end = ptr[r + 1];
  int* h = hist_s[wv];

  // hoist row-r merge inputs: overlap their latency with the gather
  unsigned char ibyte = imp[(size_t)r * 64 + lane];
  int cap = cap_arr[r];
  float pv[8];
  unpack_row_scalar(recs_p + (size_t)r * REC_DW, lane, pv);

  // ---- gather-accumulate xp for this row (exact ascending edge order) ----
  float acc[8] = {0.f, 0.f, 0.f, 0.f, 0.f, 0.f, 0.f, 0.f};
  for (int base = beg; base < end; base += 64) {
    int n = min(64, end - base);
    int cld = 0; float wld = 0.f;
    if (lane < n) { cld = ccol[base + lane]; wld = cw[base + lane]; }

    // prologue: issue edge 0's 4 loads
    uint32_t axA; float vA0, vA1, vA2; const float* vrA;
    {
      int cc = __builtin_amdgcn_readlane(cld, 0);
      const uint32_t* rc = recs_p + (size_t)cc * REC_DW;
      const float* vr = (const float*)(rc + VALS_OFF);
      axA = rc[lane];
      vA0 = vr[lane]; vA1 = vr[64 + lane]; vA2 = vr[128 + lane];
      vrA = vr;
    }
    for (int i = 0; i < n; ++i) {
      // lookahead: issue edge i+1's loads before edge i's LDS round-trip
      uint32_t axB = 0; float vB0 = 0.f, vB1 = 0.f, vB2 = 0.f;
      const float* vrB = vrA;
      if (i + 1 < n) {
        int cc = __builtin_amdgcn_readlane(cld, i + 1);
        const uint32_t* rc = recs_p + (size_t)cc * REC_DW;
        const float* vr = (const float*)(rc + VALS_OFF);
        axB = rc[lane];
        vB0 = vr[lane]; vB1 = vr[64 + lane]; vB2 = vr[128 + lane];
        vrB = vr;
      }
      float wi = readlane_f(wld, i);

      // decode edge i's positions (own aux dword only; no cross-lane dep)
      uint32_t mb = axA & 255u, mh = mb >> 4;
      int rF = (int)((axA >> 8) & 255u);
      int b0 = (int)((axA >> 16) & 511u);
      int p0 = rF;
      int p1 = rF + (int)(mb & 1u);
      int p2 = rF + __popc(mb & 3u);
      int p3 = rF + __popc(mb & 7u);
      int q0 = b0;
      int q1 = b0 + (int)(mh & 1u);
      int q2 = b0 + __popc(mh & 3u);
      int q3 = b0 + __popc(mh & 7u);

      // stage positional values in LDS (ping-pong), then rank-indexed reads
      float* vb = vbuf[wv][i & 1];
      vb[lane] = vA0; vb[64 + lane] = vA1; vb[128 + lane] = vA2;
      float a0 = vb[p0 & 255], a1 = vb[p1 & 255], a2 = vb[p2 & 255], a3 = vb[p3 & 255];
      float a4 = vb[q0 & 255], a5 = vb[q1 & 255], a6 = vb[q2 & 255], a7 = vb[q3 & 255];
      // rare fallback: row nnz > 189 (q3 is the per-lane max position)
      if (__any(q3 > 191)) {
        if (p0 > 191) a0 = vrA[p0];
        if (p1 > 191) a1 = vrA[p1];
        if (p2 > 191) a2 = vrA[p2];
        if (p3 > 191) a3 = vrA[p3];
        if (q0 > 191) a4 = vrA[q0];
        if (q1 > 191) a5 = vrA[q1];
        if (q2 > 191) a6 = vrA[q2];
        if (q3 > 191) a7 = vrA[q3];
      }
      a0 = (mb & 1u) ? a0 : 0.f;
      a1 = (mb & 2u) ? a1 : 0.f;
      a2 = (mb & 4u) ? a2 : 0.f;
      a3 = (mb & 8u) ? a3 : 0.f;
      a4 = (mh & 1u) ? a4 : 0.f;
      a5 = (mh & 2u) ? a5 : 0.f;
      a6 = (mh & 4u) ? a6 : 0.f;
      a7 = (mh & 8u) ? a7 : 0.f;
      acc[0] = acc[0] + wi * a0;
      acc[1] = acc[1] + wi * a1;
      acc[2] = acc[2] + wi * a2;
      acc[3] = acc[3] + wi * a3;
      acc[4] = acc[4] + wi * a4;
      acc[5] = acc[5] + wi * a5;
      acc[6] = acc[6] + wi * a6;
      acc[7] = acc[7] + wi * a7;

      axA = axB; vA0 = vB0; vA1 = vB1; vA2 = vB2; vrA = vrB;
    }
  }

  // ---- merge: existing (orig nonzero) entries win ----
  float val[8];
  bool ex[8];
  #pragma unroll
  for (int j = 0; j < 8; ++j) {
    ex[j] = (pv[j] != 0.f) && !((ibyte >> j) & 1);
    val[j] = ex[j] ? pv[j] : acc[j];
  }

  // ---- valid mask & count ----
  bool valid[8];
  int cnt_local = 0;
  #pragma unroll
  for (int j = 0; j < 8; ++j) {
    bool im = ((ibyte >> j) & 1) || ((val[j] != 0.f) && !ex[j]);
    valid[j] = im;
    cnt_local += im ? 1 : 0;
  }
  int nimp = cnt_local;
  #pragma unroll
  for (int off = 32; off > 0; off >>= 1) nimp += __shfl_xor(nimp, off, 64);

  bool keep_all = (nimp <= cap);
  bool keep_none = (!keep_all) && (cap <= 0);
  uint32_t key[8];
  uint32_t T = 0;
  bool use_T = false;

  if (!keep_all && !keep_none) {   // wave-uniform branch
    uint32_t goff = (uint32_t)r * (uint32_t)N_GENES;
    #pragma unroll
    for (int j = 0; j < 8; ++j) {
      int g = (j < 4) ? (4 * lane + j) : (256 + 4 * lane + (j - 4));
      uint32_t b = jax_bits_part32(k0, k1, goff + (uint32_t)g);
      key[j] = ((b >> 9) << 9) | (uint32_t)g;
    }
    h[lane] = 0; h[lane + 64] = 0; h[lane + 128] = 0; h[lane + 192] = 0;
    #pragma unroll
    for (int j = 0; j < 8; ++j)
      if (valid[j]) atomicAdd(&h[tr(key[j] >> 24)], 1);
    __threadfence_block();
    int c0 = h[lane], c1 = h[64 + lane], c2 = h[128 + lane], c3 = h[192 + lane];
    int lsum = c0 + c1 + c2 + c3;
    int incl = lsum;
    #pragma unroll
    for (int off = 1; off < 64; off <<= 1) {
      int v = __shfl_up(incl, off, 64);
      if (lane >= off) incl += v;
    }
    int excl = incl - lsum;
    int foundB = -1, foundRem = 0, cum = excl;
    if (cap > cum && cap <= cum + c0) { foundB = 4 * lane;     foundRem = cap - cum; } cum += c0;
    if (foundB < 0 && cap > cum && cap <= cum + c1) { foundB = 4 * lane + 1; foundRem = cap - cum; } cum += c1;
    if (foundB < 0 && cap > cum && cap <= cum + c2) { foundB = 4 * lane + 2; foundRem = cap - cum; } cum += c2;
    if (foundB < 0 && cap > cum && cap <= cum + c3) { foundB = 4 * lane + 3; foundRem = cap - cum; }
    unsigned long long mbal = __ballot(foundB >= 0);
    int src = __ffsll(mbal) - 1;
    int B   = __shfl(foundB, src, 64);
    int rem = __shfl(foundRem, src, 64);
    unsigned cm = 0;
    #pragma unroll
    for (int j = 0; j < 8; ++j)
      if (valid[j] && (int)(key[j] >> 24) == B) cm |= (1u << j);
    for (;;) {
      uint32_t m = 0xFFFFFFFFu;
      #pragma unroll
      for (int j = 0; j < 8; ++j)
        if (cm & (1u << j)) m = min(m, key[j]);
      #pragma unroll
      for (int off = 32; off > 0; off >>= 1)
        m = min(m, (uint32_t)__shfl_xor((int)m, off, 64));
      if (rem == 1) { T = m; break; }
      #pragma unroll
      for (int j = 0; j < 8; ++j)
        if ((cm & (1u << j)) && key[j] == m) cm &= ~(1u << j);
      rem--;
    }
    use_T = true;
  }

  // ---- apply & write ----
  float rv[8]; unsigned char ob8 = 0;
  #pragma unroll
  for (int j = 0; j < 8; ++j) {
    bool keep = valid[j] && (keep_all || (use_T && key[j] <= T));
    ob8 |= (unsigned char)(keep ? (1u << j) : 0u);
    rv[j] = (valid[j] && !keep) ? 0.f : val[j];
  }
  if (LAST) {
    float4* x4 = (float4*)(xdense + (size_t)r * N_GENES);
    x4[lane]      = make_float4(rv[0], rv[1], rv[2], rv[3]);
    x4[64 + lane] = make_float4(rv[4], rv[5], rv[6], rv[7]);
  } else {
    pack_row(recs_n + (size_t)r * REC_DW, lane, rv);
    imp[(size_t)r * 64 + lane] = ob8;
  }
}

// diagnostic: only fires if workspace is smaller than we need
__global__ void ws_probe(float* out, unsigned long long ws_bytes, unsigned long long needed) {
  if (ws_bytes < needed) out[0] = (float)ws_bytes;
}

extern "C" void kernel_launch(void* const* d_in, const int* in_sizes, int n_in,
                              void* d_out, int out_size, void* d_ws, size_t ws_size,
                              hipStream_t stream) {
  const float* x_in = (const float*)d_in[0];
  const float* ew   = (const float*)d_in[1];
  const int*   ei   = (const int*)d_in[2];
  const int*   cap  = (const int*)d_in[3];
  const int* rows = ei;
  const int* cols = ei + N_EDGES;
  float* out = (float*)d_out;

  char* ws = (char*)d_ws;
  uint32_t* recs_a = (uint32_t*)ws;         ws += RECS_BYTES;
  unsigned char* imp = (unsigned char*)ws;  ws += IMP_BYTES;
  int* cnt = (int*)ws;                      ws += CNT_BYTES;
  int* ptr = (int*)ws;                      ws += PTR_BYTES;
  int* ccol = (int*)ws;                     ws += CCOL_BYTES;
  float* cw = (float*)ws;                   ws += CW_BYTES;
  int* hist = (int*)d_ws;   // aliases recs_a: 50 MB, dead before recs_a first written

  // buffer B aliases d_out (dense out written only by the last iteration, which reads A)
  uint32_t* recs_b = (uint32_t*)d_out;

  hipMemsetAsync(hist, 0, (size_t)C_CHUNKS * N_NODES * sizeof(int), stream);
  hipMemsetAsync(imp, 0, IMP_BYTES, stream);

  chunk_hist<<<C_CHUNKS, 256, 0, stream>>>(rows, hist);
  row_scan<<<(N_NODES + 255) / 256, 256, 0, stream>>>(hist, cnt);
  scan_counts<<<1, 256, 0, stream>>>(cnt, ptr);
  scatter_par<<<C_CHUNKS, 64, 0, stream>>>(rows, cols, ew, ptr, hist, ccol, cw);
  init_pack<<<N_NODES / 4, 256, 0, stream>>>(x_in, recs_a);

  uint32_t key_it[N_ITERS][2];
  for (int it = 0; it < N_ITERS; ++it) {
    uint32_t o0, o1;
    threefry2x32(0u, 42u, 0u, (uint32_t)it, o0, o1);
    key_it[it][0] = o0; key_it[it][1] = o1;
  }

  for (int it = 0; it < N_ITERS - 1; ++it) {
    bool a2b = (it & 1) == 0;   // it0: A->B, it1: B->A, it2: A->B, it3: B->A
    prop_select<false><<<N_NODES / 4, 256, 0, stream>>>(
        a2b ? recs_a : recs_b,
        ptr, ccol, cw, imp, cap, key_it[it][0], key_it[it][1],
        a2b ? recs_b : recs_a, nullptr);
  }
  // it4 reads A, writes dense to out (clobbering B, which is dead)
  prop_select<true><<<N_NODES / 4, 256, 0, stream>>>(
      recs_a, ptr, ccol, cw, imp, cap,
      key_it[N_ITERS - 1][0], key_it[N_ITERS - 1][1],
      nullptr, out);

  ws_probe<<<1, 1, 0, stream>>>(out, (unsigned long long)ws_size,
                                (unsigned long long)WS_NEEDED);
}